// Round 4
// baseline (2553.835 us; speedup 1.0000x reference)
//
#include <hip/hip_runtime.h>
#include <hip/hip_bf16.h>

using bf16 = __hip_bfloat16;
typedef __attribute__((ext_vector_type(8))) short s16x8;
typedef __attribute__((ext_vector_type(4))) float f32x4;

constexpr int BATCH = 256, SEQ = 256, CH = 512, NH = 8, DH = 64;
constexpr int M_ALL = BATCH * SEQ;        // 65536

#define MFMA16(a, b, c) __builtin_amdgcn_mfma_f32_16x16x32_bf16((a), (b), (c), 0, 0, 0)

// ---------------------------------------------------------------------------
// Runtime dtype detection: scan x[0..63] as bf16 bit patterns. If storage is
// fp32, low half-words are uniform-random mantissa bits -> ~37% have exponent
// >= 161 (|v| > 2^34); true bf16 N(0,1) data has none. Deterministic,
// wave-uniform, graph-safe (x is pristine input).
// ---------------------------------------------------------------------------
__device__ __forceinline__ bool detect_fp32(const void* xv) {
  const unsigned int* u = (const unsigned int*)xv;
  int cnt = 0;
#pragma unroll
  for (int i = 0; i < 32; i++) {
    const unsigned int w = u[i];
    cnt += (int)(((w >> 7) & 0xFFu) >= 161u) + (int)(((w >> 23) & 0xFFu) >= 161u);
  }
  return cnt >= 3;
}

__device__ __forceinline__ short f2s(float v) {
  bf16 h = __float2bfloat16(v);
  return *reinterpret_cast<short*>(&h);
}

// 8 consecutive elements -> bf16 fragment chunk
__device__ __forceinline__ s16x8 ld8b(const void* p, size_t idx, bool f32) {
  if (f32) {
    const float* f = (const float*)p + idx;
    const float4 a = *(const float4*)f;
    const float4 b = *(const float4*)(f + 4);
    s16x8 r;
    r[0] = f2s(a.x); r[1] = f2s(a.y); r[2] = f2s(a.z); r[3] = f2s(a.w);
    r[4] = f2s(b.x); r[5] = f2s(b.y); r[6] = f2s(b.z); r[7] = f2s(b.w);
    return r;
  }
  return *(const s16x8*)((const bf16*)p + idx);
}

__device__ __forceinline__ float ldf(const void* p, size_t idx, bool f32) {
  return f32 ? ((const float*)p)[idx]
             : __bfloat162float(((const bf16*)p)[idx]);
}

__device__ __forceinline__ void stf(void* p, size_t idx, bool f32, float v) {
  if (f32) ((float*)p)[idx] = v;
  else     ((bf16*)p)[idx]  = __float2bfloat16(v);
}

// ---------------------------------------------------------------------------
// Fused per-(b,h) QKV projection + causal attention. Zero workspace, no
// global_load_lds (plain vector loads + ds_write), dtype-flexible.
// Block = one (b,h), 256 threads / 4 waves. Q/K/Vt live only in LDS.
// Head-slice output -> Ab (== d_out; out_proj is alias-safe).
// ---------------------------------------------------------------------------
__global__ __launch_bounds__(256)
void qkv_attn(const void* __restrict__ x,
              const void* __restrict__ Wq, const void* __restrict__ Wk,
              const void* __restrict__ Wv,
              const void* __restrict__ bq, const void* __restrict__ bk,
              const void* __restrict__ bv, void* __restrict__ Ab) {
  __shared__ __align__(16) bf16 Xs[SEQ * 32];     // 16 KiB k-step staging
  __shared__ __align__(16) bf16 WT[64 * 40];      // 5 KiB W^T tile [d][k]
  __shared__ __align__(16) bf16 Qs[SEQ * DH];     // 32 KiB
  __shared__ __align__(16) bf16 Ks[SEQ * DH];     // 32 KiB
  __shared__ __align__(16) bf16 Vts[DH * SEQ];    // 32 KiB (V transposed)
  __shared__ __align__(16) bf16 Pex[4][16][40];   // per-wave P exchange

  const bool f32 = detect_fp32(x);
  const int b = blockIdx.x >> 3, h = blockIdx.x & 7;
  const int tid = threadIdx.x;
  const int wave = tid >> 6, lane = tid & 63;
  const int l15 = lane & 15, lq = lane >> 4, fq = 8 * lq;

  for (int pass = 0; pass < 3; pass++) {
    const void* W = (pass == 0) ? Wq : ((pass == 1) ? Wk : Wv);
    const void* bias = (pass == 0) ? bq : ((pass == 1) ? bk : bv);
    f32x4 acc[4][4] = {};

    for (int k0 = 0; k0 < CH; k0 += 32) {
      __syncthreads();   // protect Xs/WT from prior iteration's readers
      // ---- stage Xs [256 rows][32 k]: 1024 8-elem chunks, 4/thread ----
#pragma unroll
      for (int i = 0; i < 4; i++) {
        const int g = i * 256 + tid;
        const int row = g >> 2, c = (g & 3) * 8;
        *(s16x8*)(Xs + row * 32 + c) =
            ld8b(x, (size_t)(b * SEQ + row) * CH + k0 + c, f32);
      }
      // ---- stage W^T tile [64 d][32 k]: thread = (d, kgroup of 8) ----
      {
        const int d = tid & 63, kg = tid >> 6;
        s16x8 w;
#pragma unroll
        for (int j = 0; j < 8; j++)
          w[j] = f2s(ldf(W, (size_t)(k0 + kg * 8 + j) * CH + h * DH + d, f32));
        *(s16x8*)(WT + d * 40 + kg * 8) = w;
      }
      __syncthreads();
      // ---- fragments + MFMA ----
      s16x8 af[4], bfr[4];
#pragma unroll
      for (int i = 0; i < 4; i++)
        af[i] = *(const s16x8*)(Xs + (wave * 64 + i * 16 + l15) * 32 + fq);
#pragma unroll
      for (int j = 0; j < 4; j++)
        bfr[j] = *(const s16x8*)(WT + (j * 16 + l15) * 40 + fq);
#pragma unroll
      for (int i = 0; i < 4; i++)
#pragma unroll
        for (int j = 0; j < 4; j++)
          acc[i][j] = MFMA16(af[i], bfr[j], acc[i][j]);
    }

    // epilogue: C-layout (row=4*lq+r, col=l15); XOR-swizzled 8-el chunks
#pragma unroll
    for (int j = 0; j < 4; j++) {
      const int d = j * 16 + l15;
      const float bvv = ldf(bias, h * DH + d, f32);
#pragma unroll
      for (int i = 0; i < 4; i++)
#pragma unroll
        for (int r = 0; r < 4; r++) {
          const int srow = wave * 64 + i * 16 + 4 * lq + r;
          const float v = acc[i][j][r] + bvv;
          if (pass == 0)
            Qs[srow * DH + ((((d >> 3) ^ (srow & 7))) << 3) + (d & 7)] =
                __float2bfloat16(v);
          else if (pass == 1)
            Ks[srow * DH + ((((d >> 3) ^ (srow & 7))) << 3) + (d & 7)] =
                __float2bfloat16(v);
          else
            Vts[d * SEQ + ((((srow >> 3) ^ (d & 7))) << 3) + (srow & 7)] =
                __float2bfloat16(v);
        }
    }
    __syncthreads();
  }

  // ------------------ attention: wave handles 4 query tiles ------------------
#pragma unroll 1
  for (int it = 0; it < 4; it++) {
    const int qt = it * 4 + wave;
    const int qrow = qt * 16 + l15;
    const s16x8 qf0 = *(const s16x8*)(Qs + qrow * DH + ((lq ^ (qrow & 7)) << 3));
    const s16x8 qf1 = *(const s16x8*)(Qs + qrow * DH + (((4 + lq) ^ (qrow & 7)) << 3));

    f32x4 s[16];
#pragma unroll
    for (int t = 0; t < 16; t++) {
      const int krow = t * 16 + l15;
      const s16x8 b0 = *(const s16x8*)(Ks + krow * DH + ((lq ^ (krow & 7)) << 3));
      const s16x8 b1 = *(const s16x8*)(Ks + krow * DH + (((4 + lq) ^ (krow & 7)) << 3));
      f32x4 a = {0.f, 0.f, 0.f, 0.f};
      a = MFMA16(qf0, b0, a);
      a = MFMA16(qf1, b1, a);
      s[t] = a;
    }

    // mask (additive -1e5 BEFORE /sqrt(d)) + softmax. Row q = qt*16+4lq+r.
    float mx[4] = {-3e38f, -3e38f, -3e38f, -3e38f};
#pragma unroll
    for (int t = 0; t < 16; t++) {
      const int key = t * 16 + l15;
#pragma unroll
      for (int r = 0; r < 4; r++) {
        float v = s[t][r];
        if (key > qt * 16 + 4 * lq + r) v -= 100000.0f;
        v *= 0.125f;
        s[t][r] = v;
        mx[r] = fmaxf(mx[r], v);
      }
    }
#pragma unroll
    for (int r = 0; r < 4; r++) {
      mx[r] = fmaxf(mx[r], __shfl_xor(mx[r], 1, 64));
      mx[r] = fmaxf(mx[r], __shfl_xor(mx[r], 2, 64));
      mx[r] = fmaxf(mx[r], __shfl_xor(mx[r], 4, 64));
      mx[r] = fmaxf(mx[r], __shfl_xor(mx[r], 8, 64));
    }
    float sum[4] = {0.f, 0.f, 0.f, 0.f};
#pragma unroll
    for (int t = 0; t < 16; t++)
#pragma unroll
      for (int r = 0; r < 4; r++) {
        const float p = __expf(s[t][r] - mx[r]);
        s[t][r] = p;
        sum[r] += p;
      }
#pragma unroll
    for (int r = 0; r < 4; r++) {
      sum[r] += __shfl_xor(sum[r], 1, 64);
      sum[r] += __shfl_xor(sum[r], 2, 64);
      sum[r] += __shfl_xor(sum[r], 4, 64);
      sum[r] += __shfl_xor(sum[r], 8, 64);
      sum[r] = 1.0f / sum[r];
    }

    // PV: P C-layout -> A-layout via LDS round-trip (plain __syncthreads,
    // uniform trip counts), 32 keys/step
    f32x4 o[4] = {};
#pragma unroll 1
    for (int kk = 0; kk < 8; kk++) {
#pragma unroll
      for (int tt = 0; tt < 2; tt++)
#pragma unroll
        for (int r = 0; r < 4; r++)
          Pex[wave][4 * lq + r][tt * 16 + l15] =
              __float2bfloat16(s[kk * 2 + tt][r] * sum[r]);
      __syncthreads();
      const s16x8 pf = *(const s16x8*)&Pex[wave][l15][fq];
#pragma unroll
      for (int j = 0; j < 4; j++) {
        const int d = j * 16 + l15;
        const int ch = (kk * 4 + lq) ^ (d & 7);
        const s16x8 vb = *(const s16x8*)(Vts + d * SEQ + (ch << 3));
        o[j] = MFMA16(pf, vb, o[j]);
      }
      __syncthreads();
    }

    // write head slice into Ab [B*S, CH]  (Ab == d_out)
#pragma unroll
    for (int j = 0; j < 4; j++)
#pragma unroll
      for (int r = 0; r < 4; r++) {
        const int p = qt * 16 + 4 * lq + r;
        const int d = j * 16 + l15;
        stf(Ab, (size_t)(b * SEQ + p) * CH + h * DH + d, f32, o[j][r]);
      }
  }
}

// ---------------------------------------------------------------------------
// Out-projection, zero-workspace + ALIAS-SAFE (Ab == out): block owns 128
// rows exclusively; all reads precede all writes. 512 blocks x 512 threads.
// ---------------------------------------------------------------------------
__global__ __launch_bounds__(512)
void out_proj(const void* __restrict__ Ab, const void* __restrict__ Wo,
              const void* __restrict__ bo, void* __restrict__ out,
              const void* __restrict__ x /*dtype probe only*/) {
  __shared__ __align__(16) bf16 As[128 * 40];     // 10 KiB padded
  __shared__ __align__(16) bf16 WT2[512 * 40];    // 40 KiB W^T tile [n][k]
  const bool f32 = detect_fp32(x);
  const int m0 = blockIdx.x * 128;
  const int tid = threadIdx.x;
  const int wave = tid >> 6, lane = tid & 63;
  const int l15 = lane & 15, lq = lane >> 4, fq = 8 * lq;
  const int mh = wave >> 2, nq = wave & 3;        // 2 m-halves x 4 n-quads

  f32x4 acc[4][8] = {};

  for (int kk = 0; kk < 16; kk++) {
    __syncthreads();   // prior iteration's LDS reads complete
    // ---- stage As [128 rows][32 k]: 512 chunks of 8, 1/thread ----
    {
      const int row = tid >> 2, c = (tid & 3) * 8;
      *(s16x8*)(As + row * 40 + c) =
          ld8b(Ab, (size_t)(m0 + row) * CH + kk * 32 + c, f32);
    }
    // ---- stage W^T tile [512 n][32 k]: thread = one n, coalesced rows ----
    {
      const int n = tid;
#pragma unroll
      for (int kg = 0; kg < 4; kg++) {
        s16x8 w;
#pragma unroll
        for (int j = 0; j < 8; j++)
          w[j] = f2s(ldf(Wo, (size_t)(kk * 32 + kg * 8 + j) * CH + n, f32));
        *(s16x8*)(WT2 + n * 40 + kg * 8) = w;
      }
    }
    __syncthreads();
    // ---- fragments + MFMA ----
    s16x8 af[4], bfr[8];
#pragma unroll
    for (int i = 0; i < 4; i++)
      af[i] = *(const s16x8*)(As + (mh * 64 + i * 16 + l15) * 40 + fq);
#pragma unroll
    for (int j = 0; j < 8; j++)
      bfr[j] = *(const s16x8*)(WT2 + (nq * 128 + j * 16 + l15) * 40 + fq);
#pragma unroll
    for (int j = 0; j < 8; j++)
#pragma unroll
      for (int i = 0; i < 4; i++)
        acc[i][j] = MFMA16(af[i], bfr[j], acc[i][j]);
  }

#pragma unroll
  for (int j = 0; j < 8; j++) {
    const int n = nq * 128 + j * 16 + l15;
    const float bvv = ldf(bo, n, f32);
#pragma unroll
    for (int i = 0; i < 4; i++)
#pragma unroll
      for (int r = 0; r < 4; r++) {
        const int m = m0 + mh * 64 + i * 16 + 4 * lq + r;
        stf(out, (size_t)m * CH + n, f32, acc[i][j][r] + bvv);
      }
  }
}

// ---------------------------------------------------------------------------
extern "C" void kernel_launch(void* const* d_in, const int* in_sizes, int n_in,
                              void* d_out, int out_size, void* d_ws, size_t ws_size,
                              hipStream_t stream) {
  const void* x  = d_in[0];
  const void* Wq = d_in[1];
  const void* bq = d_in[2];
  const void* Wk = d_in[3];
  const void* bk = d_in[4];
  const void* Wv = d_in[5];
  const void* bv = d_in[6];
  const void* Wo = d_in[7];
  const void* bo = d_in[8];

  // Zero-workspace: attention output aliases d_out (out_proj is alias-safe
  // via exclusive full-row block ownership; all reads precede writes).
  void* Ab = d_out;

  qkv_attn<<<dim3(BATCH * NH), 256, 0, stream>>>(x, Wq, Wk, Wv, bq, bk, bv, Ab);

  out_proj<<<dim3(M_ALL / 128), 512, 0, stream>>>(Ab, Wo, bo, d_out, x);
}